// Round 15
// baseline (293.645 us; speedup 1.0000x reference)
//
#include <hip/hip_runtime.h>
#include <math.h>

typedef __attribute__((ext_vector_type(4))) float f32x4;
typedef __attribute__((ext_vector_type(8))) _Float16 h16x8;
typedef __attribute__((ext_vector_type(8))) short s16x8;
typedef __attribute__((ext_vector_type(4))) short s16x4;

__device__ inline unsigned short f2h(float f) {
    union { _Float16 h; unsigned short u; } v; v.h = (_Float16)f; return v.u;
}
__device__ inline float h2f(unsigned short u) {
    union { unsigned short u; _Float16 h; } v; v.u = u; return (float)v.h;
}

__device__ inline void async16(const void* g, void* l) {
    __builtin_amdgcn_global_load_lds(
        (const __attribute__((address_space(1))) unsigned int*)g,
        (__attribute__((address_space(3))) unsigned int*)l, 16, 0, 0);
}

// bijective XCD-aware workgroup swizzle (m204 form)
__device__ inline void xcd_swizzle(int& bx, int& by, int& bz) {
    const long gx = gridDim.x, gy = gridDim.y;
    const long nwg = gx * gy * (long)gridDim.z;
    const long hw  = ((long)blockIdx.z * gy + blockIdx.y) * gx + blockIdx.x;
    const long qq = nwg >> 3, rr = nwg & 7;
    const long xcd = hw & 7, pos = hw >> 3;
    const long lg = (xcd < rr) ? xcd * (qq + 1) + pos
                               : rr * (qq + 1) + (xcd - rr) * qq + pos;
    bx = (int)(lg % gx);
    const long rem = lg / gx;
    by = (int)(rem % gy);
    bz = (int)(rem / gy);
}

// ===== gemm256w4: 256x256 tile, BK=32, 4 waves of 128x128 each =====
// Rationale (r15): GEMM is LDS-BW-bound (r14: 0 conflicts, dur unchanged).
// Square 128x128 per-wave tiles cut LDS bytes/MFMA 0.69 -> 0.375 KB.
// LDS 64 KB: buf d at d*32768; A (16 KB) at +0, B (16 KB) at +16384.
// PAIRED-ROW layout (r14, measured 0-conflict): tile row r, 16B chunk q:
//   lr = r>>1 ; slot = (((r&1)<<2)|q) ^ (lr&7) ; byte = lr*128 + slot*16
// Staging stays pure global_load_lds (r6/r11 lesson x3: never fuse cvt).
#define BK2 32

__device__ inline h16x8 ld_frag32(const char* smem, unsigned base, int row, int q) {
    const int lr = row >> 1;
    const int slot = (((row & 1) << 2) | q) ^ (lr & 7);
    return *(const h16x8*)(smem + base + (unsigned)(lr * 128 + slot * 16));
}

template<int OM>
__global__ __launch_bounds__(256, 1)
void gemm256w4(const unsigned short* __restrict__ A,
               const unsigned short* __restrict__ B,
               const float* __restrict__ bias,
               void* __restrict__ C, int N, int lenK, int pitch,
               long sA, long sB, long sC, long sBias, float scale)
{
    __shared__ __align__(16) char smem[65536];

    const int tid  = threadIdx.x;
    const int wv   = tid >> 6;
    const int lane = tid & 63;
    const int wr = wv >> 1, wc = wv & 1;       // 2x2 waves, 128x128 each
    const int lrow = lane & 15;
    const int kq   = lane >> 4;                // k 16B-chunk 0..3

    int bx, by, bz; xcd_swizzle(bx, by, bz);
    const int n0 = bx * 256;
    const int m0 = by * 256;

    const unsigned short* Ag = A + (long)bz * sA;
    const unsigned short* Bg = B + (long)bz * sB;
    const int NT = lenK / BK2;

    // inverse of paired-row permutation: linear chunk i -> (tile row, chunk q)
    auto srcRQ = [](int i, int& r, int& q) {
        int lr = i >> 3;
        int sl = (i & 7) ^ (lr & 7);
        r = (lr << 1) | (sl >> 2);
        q = sl & 3;
    };

    auto stage = [&](int t) {
        const unsigned db = (unsigned)((t & 1) * 32768);
#pragma unroll
        for (int l = 0; l < 4; ++l) {
            int r, q; srcRQ(l * 256 + tid, r, q);
            async16((const char*)Ag + ((long)(m0 + r) * pitch + t * BK2 + q * 8) * 2,
                    smem + db + (unsigned)(l * 4096) + (unsigned)(wv << 10));
        }
#pragma unroll
        for (int l = 0; l < 4; ++l) {
            int r, q; srcRQ(l * 256 + tid, r, q);
            async16((const char*)Bg + ((long)(n0 + r) * pitch + t * BK2 + q * 8) * 2,
                    smem + db + 16384u + (unsigned)(l * 4096) + (unsigned)(wv << 10));
        }
    };

    f32x4 acc[8][8];
#pragma unroll
    for (int i = 0; i < 8; ++i)
#pragma unroll
        for (int j = 0; j < 8; ++j) acc[i][j] = (f32x4){0.f, 0.f, 0.f, 0.f};

    stage(0);
    __syncthreads();

#pragma unroll 2
    for (int t = 0; t < NT; ++t) {
        const unsigned db = (unsigned)((t & 1) * 32768);
        if (t + 1 < NT) stage(t + 1);       // other buffer; safe across 1 barrier
        h16x8 afr[8], bfr[8];
#pragma unroll
        for (int f = 0; f < 8; ++f) {
            afr[f] = ld_frag32(smem, db,          wr * 128 + f * 16 + lrow, kq);
            bfr[f] = ld_frag32(smem, db + 16384u, wc * 128 + f * 16 + lrow, kq);
        }
#pragma unroll
        for (int mi = 0; mi < 8; ++mi)
#pragma unroll
            for (int j = 0; j < 8; ++j)
                acc[mi][j] = __builtin_amdgcn_mfma_f32_16x16x32_f16(
                    afr[mi], bfr[j], acc[mi][j], 0, 0, 0);
        __syncthreads();                    // drains vmcnt (stage t+1) + lgkm
    }

#pragma unroll
    for (int j = 0; j < 8; ++j) {
        const int col = n0 + wc * 128 + j * 16 + lrow;
        const float bb = bias ? bias[(long)bz * sBias + col] : 0.f;
#pragma unroll
        for (int mi = 0; mi < 8; ++mi) {
#pragma unroll
            for (int r = 0; r < 4; ++r) {
                const long row = m0 + wr * 128 + mi * 16 + (lane >> 4) * 4 + r;
                const float v = acc[mi][j][r] * scale + bb;
                const long idx = (long)bz * sC + row * (long)N + col;
                if constexpr (OM == 0) ((float*)C)[idx] = v;
                else                   ((unsigned short*)C)[idx] = f2h(v);
            }
        }
    }
}

// ======================= small kernels =======================

// query+keys f32 -> f16 (nontemporal), with v[r] = keys_row . w2 fused into the
// keys half (each block covers exactly 2 rows; dot computed from f32 values).
__global__ __launch_bounds__(256)
void conv2_f16(const float* __restrict__ a, const float* __restrict__ b,
               unsigned short* __restrict__ oa, unsigned short* __restrict__ ob,
               const float* __restrict__ w2, float* __restrict__ vvec)
{
    const long i = ((long)blockIdx.x * 256 + threadIdx.x) * 8;
    const float* in = blockIdx.y ? b : a;
    unsigned short* out = blockIdx.y ? ob : oa;
    f32x4 v0 = __builtin_nontemporal_load((const f32x4*)(in + i));
    f32x4 v1 = __builtin_nontemporal_load((const f32x4*)(in + i + 4));
    s16x8 o = {(short)f2h(v0.x), (short)f2h(v0.y), (short)f2h(v0.z), (short)f2h(v0.w),
               (short)f2h(v1.x), (short)f2h(v1.y), (short)f2h(v1.z), (short)f2h(v1.w)};
    __builtin_nontemporal_store(o, (s16x8*)(out + i));

    if (blockIdx.y) {   // keys half: fused column-bias dot product
        const int col = (threadIdx.x & 127) * 8;
        f32x4 w0 = *(const f32x4*)(w2 + col);
        f32x4 w1 = *(const f32x4*)(w2 + col + 4);
        float s = v0.x * w0.x + v0.y * w0.y + v0.z * w0.z + v0.w * w0.w
                + v1.x * w1.x + v1.y * w1.y + v1.z * w1.z + v1.w * w1.w;
#pragma unroll
        for (int off = 1; off < 64; off <<= 1) s += __shfl_xor(s, off);
        __shared__ float red[4];
        const int wave = threadIdx.x >> 6, lane = threadIdx.x & 63;
        if (lane == 0) red[wave] = s;
        __syncthreads();
        if (threadIdx.x < 2)    // rows 2*bx, 2*bx+1 (waves 0+1 = row0, 2+3 = row1)
            vvec[(long)blockIdx.x * 2 + threadIdx.x] =
                red[threadIdx.x * 2] + red[threadIdx.x * 2 + 1];
    }
}

__global__ __launch_bounds__(256)
void conv_f16(const float* __restrict__ in, unsigned short* __restrict__ out, int n)
{
    int i = (blockIdx.x * 256 + threadIdx.x) * 4;
    if (i >= n) return;
    f32x4 v = *(const f32x4*)(in + i);
    s16x4 o = {(short)f2h(v.x), (short)f2h(v.y), (short)f2h(v.z), (short)f2h(v.w)};
    *(s16x4*)(out + i) = o;
}

// values [16][1024][1024] f32 -> f16 transpose, grid-stride over z
__global__ __launch_bounds__(256)
void transpose_vals(const float* __restrict__ in, unsigned short* __restrict__ out)
{
    __shared__ float tile[32][33];
    const int h0 = blockIdx.x * 32, t0 = blockIdx.y * 32;
    for (int z = blockIdx.z; z < 16; z += gridDim.z) {
        const long base = (long)z * 1024 * 1024;
        __syncthreads();
        for (int i = threadIdx.y; i < 32; i += 8)
            tile[i][threadIdx.x] = in[base + (long)(t0 + i) * 1024 + h0 + threadIdx.x];
        __syncthreads();
        for (int i = threadIdx.y; i < 32; i += 8)
            out[base + (long)(h0 + i) * 1024 + t0 + threadIdx.x] = f2h(tile[threadIdx.x][i]);
    }
}

// two 1024x1024 transposes in one launch (z=0: Wq->WqT, z=1: Wk->WkT)
__global__ __launch_bounds__(256)
void transpose2_f16(const float* __restrict__ inA, const float* __restrict__ inB,
                    unsigned short* __restrict__ outA, unsigned short* __restrict__ outB)
{
    __shared__ float tile[32][33];
    const float* in = blockIdx.z ? inB : inA;
    unsigned short* out = blockIdx.z ? outB : outA;
    const int h0 = blockIdx.x * 32, t0 = blockIdx.y * 32;
    for (int i = threadIdx.y; i < 32; i += 8)
        tile[i][threadIdx.x] = in[(long)(t0 + i) * 1024 + h0 + threadIdx.x];
    __syncthreads();
    for (int i = threadIdx.y; i < 32; i += 8)
        out[(long)(h0 + i) * 1024 + t0 + threadIdx.x] = f2h(tile[threadIdx.x][i]);
}

// w2[h] = sum_o Wk[o][h] * bq[o]
__global__ __launch_bounds__(256)
void w2_kernel(const float* __restrict__ Wk, const float* __restrict__ bq,
               float* __restrict__ w2)
{
    __shared__ float part[4][64];
    const int tx = threadIdx.x & 63;
    const int ty = threadIdx.x >> 6;
    const int h  = blockIdx.x * 64 + tx;
    float s = 0.f;
    for (int o = ty * 256; o < ty * 256 + 256; ++o)
        s = fmaf(Wk[(long)o * 1024 + h], bq[o], s);
    part[ty][tx] = s;
    __syncthreads();
    if (ty == 0) w2[h] = part[0][tx] + part[1][tx] + part[2][tx] + part[3][tx];
}

// MT f16 = sum of 4 f32 partial slabs
__global__ __launch_bounds__(256)
void reduce4(const float* __restrict__ p, unsigned short* __restrict__ MT)
{
    const long i = ((long)blockIdx.x * 256 + threadIdx.x) * 4;
    const long S = 1024L * 1024;
    f32x4 a = *(const f32x4*)(p + i);
    f32x4 b = *(const f32x4*)(p + S + i);
    f32x4 c = *(const f32x4*)(p + 2 * S + i);
    f32x4 d = *(const f32x4*)(p + 3 * S + i);
    s16x4 o = {(short)f2h(a.x + b.x + c.x + d.x), (short)f2h(a.y + b.y + c.y + d.y),
               (short)f2h(a.z + b.z + c.z + d.z), (short)f2h(a.w + b.w + c.w + d.w)};
    *(s16x4*)(MT + i) = o;
}

// wave-per-row in-place softmax on fp16 logits (16384 rows x 1024), no LDS
__global__ __launch_bounds__(256)
void softmax_wave(unsigned short* __restrict__ S)
{
    const int wave = threadIdx.x >> 6, lane = threadIdx.x & 63;
    for (long row = (long)blockIdx.x * 4 + wave; row < 16384; row += (long)gridDim.x * 4) {
        unsigned short* p = S + row * 1024;
        s16x8 ra = *(s16x8*)(p + lane * 8);
        s16x8 rb = *(s16x8*)(p + 512 + lane * 8);
        float va[8], vb[8];
        float m = -3.0e38f;
#pragma unroll
        for (int e = 0; e < 8; ++e) {
            va[e] = h2f((unsigned short)ra[e]); m = fmaxf(m, va[e]);
            vb[e] = h2f((unsigned short)rb[e]); m = fmaxf(m, vb[e]);
        }
#pragma unroll
        for (int off = 1; off < 64; off <<= 1) m = fmaxf(m, __shfl_xor(m, off));
        float s = 0.f;
#pragma unroll
        for (int e = 0; e < 8; ++e) {
            va[e] = expf(va[e] - m); s += va[e];
            vb[e] = expf(vb[e] - m); s += vb[e];
        }
#pragma unroll
        for (int off = 1; off < 64; off <<= 1) s += __shfl_xor(s, off);
        const float inv = 1.f / s;
        s16x8 oa, ob;
#pragma unroll
        for (int e = 0; e < 8; ++e) {
            oa[e] = (short)f2h(va[e] * inv);
            ob[e] = (short)f2h(vb[e] * inv);
        }
        *(s16x8*)(p + lane * 8)       = oa;
        *(s16x8*)(p + 512 + lane * 8) = ob;
    }
}

extern "C" void kernel_launch(void* const* d_in, const int* in_sizes, int n_in,
                              void* d_out, int out_size, void* d_ws, size_t ws_size,
                              hipStream_t stream)
{
    const float* query  = (const float*)d_in[0];
    const float* keys   = (const float*)d_in[1];
    const float* values = (const float*)d_in[2];
    const float* Wq     = (const float*)d_in[3];
    const float* bq     = (const float*)d_in[4];
    const float* Wk     = (const float*)d_in[5];
    const float* bk     = (const float*)d_in[6];   // drops out of softmax
    const float* Wo     = (const float*)d_in[7];
    const float* bo     = (const float*)d_in[8];
    (void)bk;

    const int  T = 1024, H = 1024;
    const long NE = 16384L * 1024;
    const long NW = 1024L * 1024;

    size_t need = (size_t)(NE * 4 + NW * 12 + 40960) * sizeof(unsigned short);
    if (ws_size < need) return;

    unsigned short* ws   = (unsigned short*)d_ws;
    unsigned short* Xq   = ws;                 // -> sc after P1
    unsigned short* Xk   = Xq + NE;
    unsigned short* vT   = Xk + NE;
    unsigned short* P1   = vT + NE;            // -> ctx after scores
    unsigned short* WqT  = P1 + NE;
    unsigned short* WkT  = WqT + NW;
    unsigned short* Woh  = WkT + NW;
    unsigned short* MT   = Woh + NW;
    float*          part = (float*)(MT + NW);
    float*          w2   = (float*)(MT + NW * 9);
    float*          vvec = w2 + 1024;
    unsigned short* sc   = Xq;
    unsigned short* ctx  = P1;

    // ---- prep (w2 first: conv2's keys half consumes it) ----
    w2_kernel<<<16, 256, 0, stream>>>(Wk, bq, w2);
    conv2_f16<<<dim3(8192, 2, 1), 256, 0, stream>>>(query, keys, Xq, Xk, w2, vvec);
    transpose2_f16<<<dim3(32, 32, 2), dim3(32, 8), 0, stream>>>(Wq, Wk, WqT, WkT);
    conv_f16<<<1024, 256, 0, stream>>>(Wo, Woh, (int)NW);
    transpose_vals<<<dim3(32, 32, 4), dim3(32, 8), 0, stream>>>(values, vT);

    // ---- MT = Wk^T * Wq  (split-K=4, grid 4x4x4 = 64 blocks) ----
    gemm256w4<0><<<dim3(4, 4, 4), 256, 0, stream>>>(
        WkT, WqT, nullptr, part, 1024, 256, 1024, 256, 256, (long)NW, 0, 1.f);
    reduce4<<<1024, 256, 0, stream>>>(part, MT);

    // ---- P1 = Xq . MT^T  (grid 4x64 = 256 = 1 block/CU) ----
    gemm256w4<1><<<dim3(4, 64, 1), 256, 0, stream>>>(
        Xq, MT, nullptr, P1, H, H, H, 0, 0, 0, 0, 1.f);

    // ---- scores = P1 . Xk^T + v[s]  (batched, grid 4x4x16 = 256) ----
    gemm256w4<1><<<dim3(4, 4, 16), 256, 0, stream>>>(
        P1, Xk, vvec, sc, T, H, H,
        (long)T * H, (long)T * H, (long)T * T, (long)T, 1.f);

    // ---- softmax in place (wave per row) ----
    softmax_wave<<<2048, 256, 0, stream>>>(sc);

    // ---- ctx = attn . vT^T / 32  (batched) ----
    gemm256w4<1><<<dim3(4, 4, 16), 256, 0, stream>>>(
        sc, vT, nullptr, ctx, H, T, T,
        (long)T * T, (long)T * H, (long)T * H, 0, 1.f / 32.f);

    // ---- out = ctx . Wo^T + bo ----
    gemm256w4<0><<<dim3(4, 64, 1), 256, 0, stream>>>(
        ctx, Woh, bo, d_out, H, H, H, 0, 0, 0, 0, 1.f);
}

// Round 16
// 282.838 us; speedup vs baseline: 1.0382x; 1.0382x over previous
//
#include <hip/hip_runtime.h>
#include <math.h>

typedef __attribute__((ext_vector_type(4))) float f32x4;
typedef __attribute__((ext_vector_type(8))) _Float16 h16x8;
typedef __attribute__((ext_vector_type(8))) short s16x8;
typedef __attribute__((ext_vector_type(4))) short s16x4;

__device__ inline unsigned short f2h(float f) {
    union { _Float16 h; unsigned short u; } v; v.h = (_Float16)f; return v.u;
}
__device__ inline float h2f(unsigned short u) {
    union { unsigned short u; _Float16 h; } v; v.u = u; return (float)v.h;
}

__device__ inline void async16(const void* g, void* l) {
    __builtin_amdgcn_global_load_lds(
        (const __attribute__((address_space(1))) unsigned int*)g,
        (__attribute__((address_space(3))) unsigned int*)l, 16, 0, 0);
}

// bijective XCD-aware workgroup swizzle (m204 form)
__device__ inline void xcd_swizzle(int& bx, int& by, int& bz) {
    const long gx = gridDim.x, gy = gridDim.y;
    const long nwg = gx * gy * (long)gridDim.z;
    const long hw  = ((long)blockIdx.z * gy + blockIdx.y) * gx + blockIdx.x;
    const long qq = nwg >> 3, rr = nwg & 7;
    const long xcd = hw & 7, pos = hw >> 3;
    const long lg = (xcd < rr) ? xcd * (qq + 1) + pos
                               : rr * (qq + 1) + (xcd - rr) * qq + pos;
    bx = (int)(lg % gx);
    const long rem = lg / gx;
    by = (int)(rem % gy);
    bz = (int)(rem / gy);
}

// ===== gemm128: 128x256, BK=32, 48 KiB LDS dbuf — BEST MEASURED (r14) =====
// 6 structural experiments (8-phase, ping-pong, reorder, occupancy, conflicts,
// LDS-traffic) all land 670-764 TF at K=1024; this config is the optimum:
// VGPR 56, 6 waves/SIMD, 0 bank conflicts.
// LDS: buf d at d*24576; A (8 KB) at +0; B (16 KB) at +8192.
// PAIRED-ROW layout (r14, measured 0-conflict): tile row r, 16B chunk q:
//   lr = r>>1 ; slot = (((r&1)<<2)|q) ^ (lr&7) ; byte = lr*128 + slot*16
// NOTE (r6/r11/r15 lessons): never fuse cvt into staging; never drop occupancy
// below ~2 waves/SIMD for bigger tiles.
#define BK2 32

__device__ inline h16x8 ld_frag32(const char* smem, unsigned base, int row, int q) {
    const int lr = row >> 1;
    const int slot = (((row & 1) << 2) | q) ^ (lr & 7);
    return *(const h16x8*)(smem + base + (unsigned)(lr * 128 + slot * 16));
}

template<int OM>
__global__ __launch_bounds__(512, 4)
void gemm128(const unsigned short* __restrict__ A,
             const unsigned short* __restrict__ B,
             const float* __restrict__ bias,
             void* __restrict__ C, int N, int lenK, int pitch,
             long sA, long sB, long sC, long sBias, float scale)
{
    __shared__ __align__(16) char smem[49152];

    const int tid  = threadIdx.x;
    const int wv   = tid >> 6;
    const int lane = tid & 63;
    const int wr = wv >> 2, wc = wv & 3;       // 2M x 4N waves, 64x64 each
    const int lrow = lane & 15;
    const int kq   = lane >> 4;                // k 16B-chunk 0..3

    int bx, by, bz; xcd_swizzle(bx, by, bz);
    const int n0 = bx * 256;
    const int m0 = by * 128;

    const unsigned short* Ag = A + (long)bz * sA;
    const unsigned short* Bg = B + (long)bz * sB;
    const int NT = lenK / BK2;

    // inverse of paired-row permutation: linear chunk i -> (tile row, chunk q)
    auto srcRQ = [](int i, int& r, int& q) {
        int lr = i >> 3;
        int sl = (i & 7) ^ (lr & 7);
        r = (lr << 1) | (sl >> 2);
        q = sl & 3;
    };

    auto stage = [&](int t) {
        const unsigned db = (unsigned)((t & 1) * 24576);
        {
            int r, q; srcRQ(tid, r, q);
            async16((const char*)Ag + ((long)(m0 + r) * pitch + t * BK2 + q * 8) * 2,
                    smem + db + (unsigned)(wv << 10));
        }
#pragma unroll
        for (int l = 0; l < 2; ++l) {
            int r, q; srcRQ(l * 512 + tid, r, q);
            async16((const char*)Bg + ((long)(n0 + r) * pitch + t * BK2 + q * 8) * 2,
                    smem + db + 8192u + (unsigned)(l * 8192) + (unsigned)(wv << 10));
        }
    };

    f32x4 acc[4][4];
#pragma unroll
    for (int i = 0; i < 4; ++i)
#pragma unroll
        for (int j = 0; j < 4; ++j) acc[i][j] = (f32x4){0.f, 0.f, 0.f, 0.f};

    const unsigned Abase = (unsigned)(wr * 4096);
    const unsigned Bbase = 8192u + (unsigned)(wc * 4096);

    stage(0);
    __syncthreads();

#pragma unroll 2
    for (int t = 0; t < NT; ++t) {
        const unsigned db = (unsigned)((t & 1) * 24576);
        if (t + 1 < NT) stage(t + 1);       // other buffer; safe across 1 barrier
        h16x8 afr[4], bfr[4];
#pragma unroll
        for (int f = 0; f < 4; ++f) {
            afr[f] = ld_frag32(smem, db + Abase, f * 16 + lrow, kq);
            bfr[f] = ld_frag32(smem, db + Bbase, f * 16 + lrow, kq);
        }
#pragma unroll
        for (int mi = 0; mi < 4; ++mi)
#pragma unroll
            for (int j = 0; j < 4; ++j)
                acc[mi][j] = __builtin_amdgcn_mfma_f32_16x16x32_f16(
                    afr[mi], bfr[j], acc[mi][j], 0, 0, 0);
        __syncthreads();                    // drains vmcnt (stage t+1) + lgkm
    }

#pragma unroll
    for (int j = 0; j < 4; ++j) {
        const int col = n0 + wc * 64 + j * 16 + lrow;
        const float bb = bias ? bias[(long)bz * sBias + col] : 0.f;
#pragma unroll
        for (int mi = 0; mi < 4; ++mi) {
#pragma unroll
            for (int r = 0; r < 4; ++r) {
                const long row = m0 + wr * 64 + mi * 16 + (lane >> 4) * 4 + r;
                const float v = acc[mi][j][r] * scale + bb;
                const long idx = (long)bz * sC + row * (long)N + col;
                if constexpr (OM == 0) ((float*)C)[idx] = v;
                else                   ((unsigned short*)C)[idx] = f2h(v);
            }
        }
    }
}

// ======================= small kernels =======================

// query+keys f32 -> f16 (nontemporal), with v[r] = keys_row . w2 fused into the
// keys half (each block covers exactly 2 rows; dot computed from f32 values).
// r15-verified correct (absmax unchanged); saves the standalone matvec dispatch.
__global__ __launch_bounds__(256)
void conv2_f16(const float* __restrict__ a, const float* __restrict__ b,
               unsigned short* __restrict__ oa, unsigned short* __restrict__ ob,
               const float* __restrict__ w2, float* __restrict__ vvec)
{
    const long i = ((long)blockIdx.x * 256 + threadIdx.x) * 8;
    const float* in = blockIdx.y ? b : a;
    unsigned short* out = blockIdx.y ? ob : oa;
    f32x4 v0 = __builtin_nontemporal_load((const f32x4*)(in + i));
    f32x4 v1 = __builtin_nontemporal_load((const f32x4*)(in + i + 4));
    s16x8 o = {(short)f2h(v0.x), (short)f2h(v0.y), (short)f2h(v0.z), (short)f2h(v0.w),
               (short)f2h(v1.x), (short)f2h(v1.y), (short)f2h(v1.z), (short)f2h(v1.w)};
    __builtin_nontemporal_store(o, (s16x8*)(out + i));

    if (blockIdx.y) {   // keys half: fused column-bias dot product
        const int col = (threadIdx.x & 127) * 8;
        f32x4 w0 = *(const f32x4*)(w2 + col);
        f32x4 w1 = *(const f32x4*)(w2 + col + 4);
        float s = v0.x * w0.x + v0.y * w0.y + v0.z * w0.z + v0.w * w0.w
                + v1.x * w1.x + v1.y * w1.y + v1.z * w1.z + v1.w * w1.w;
#pragma unroll
        for (int off = 1; off < 64; off <<= 1) s += __shfl_xor(s, off);
        __shared__ float red[4];
        const int wave = threadIdx.x >> 6, lane = threadIdx.x & 63;
        if (lane == 0) red[wave] = s;
        __syncthreads();
        if (threadIdx.x < 2)    // rows 2*bx, 2*bx+1 (waves 0+1 = row0, 2+3 = row1)
            vvec[(long)blockIdx.x * 2 + threadIdx.x] =
                red[threadIdx.x * 2] + red[threadIdx.x * 2 + 1];
    }
}

__global__ __launch_bounds__(256)
void conv_f16(const float* __restrict__ in, unsigned short* __restrict__ out, int n)
{
    int i = (blockIdx.x * 256 + threadIdx.x) * 4;
    if (i >= n) return;
    f32x4 v = *(const f32x4*)(in + i);
    s16x4 o = {(short)f2h(v.x), (short)f2h(v.y), (short)f2h(v.z), (short)f2h(v.w)};
    *(s16x4*)(out + i) = o;
}

// values [16][1024][1024] f32 -> f16 transpose, grid-stride over z
__global__ __launch_bounds__(256)
void transpose_vals(const float* __restrict__ in, unsigned short* __restrict__ out)
{
    __shared__ float tile[32][33];
    const int h0 = blockIdx.x * 32, t0 = blockIdx.y * 32;
    for (int z = blockIdx.z; z < 16; z += gridDim.z) {
        const long base = (long)z * 1024 * 1024;
        __syncthreads();
        for (int i = threadIdx.y; i < 32; i += 8)
            tile[i][threadIdx.x] = in[base + (long)(t0 + i) * 1024 + h0 + threadIdx.x];
        __syncthreads();
        for (int i = threadIdx.y; i < 32; i += 8)
            out[base + (long)(h0 + i) * 1024 + t0 + threadIdx.x] = f2h(tile[threadIdx.x][i]);
    }
}

// two 1024x1024 transposes in one launch (z=0: Wq->WqT, z=1: Wk->WkT)
__global__ __launch_bounds__(256)
void transpose2_f16(const float* __restrict__ inA, const float* __restrict__ inB,
                    unsigned short* __restrict__ outA, unsigned short* __restrict__ outB)
{
    __shared__ float tile[32][33];
    const float* in = blockIdx.z ? inB : inA;
    unsigned short* out = blockIdx.z ? outB : outA;
    const int h0 = blockIdx.x * 32, t0 = blockIdx.y * 32;
    for (int i = threadIdx.y; i < 32; i += 8)
        tile[i][threadIdx.x] = in[(long)(t0 + i) * 1024 + h0 + threadIdx.x];
    __syncthreads();
    for (int i = threadIdx.y; i < 32; i += 8)
        out[(long)(h0 + i) * 1024 + t0 + threadIdx.x] = f2h(tile[threadIdx.x][i]);
}

// w2[h] = sum_o Wk[o][h] * bq[o]
__global__ __launch_bounds__(256)
void w2_kernel(const float* __restrict__ Wk, const float* __restrict__ bq,
               float* __restrict__ w2)
{
    __shared__ float part[4][64];
    const int tx = threadIdx.x & 63;
    const int ty = threadIdx.x >> 6;
    const int h  = blockIdx.x * 64 + tx;
    float s = 0.f;
    for (int o = ty * 256; o < ty * 256 + 256; ++o)
        s = fmaf(Wk[(long)o * 1024 + h], bq[o], s);
    part[ty][tx] = s;
    __syncthreads();
    if (ty == 0) w2[h] = part[0][tx] + part[1][tx] + part[2][tx] + part[3][tx];
}

// MT f16 = sum of 4 f32 partial slabs
__global__ __launch_bounds__(256)
void reduce4(const float* __restrict__ p, unsigned short* __restrict__ MT)
{
    const long i = ((long)blockIdx.x * 256 + threadIdx.x) * 4;
    const long S = 1024L * 1024;
    f32x4 a = *(const f32x4*)(p + i);
    f32x4 b = *(const f32x4*)(p + S + i);
    f32x4 c = *(const f32x4*)(p + 2 * S + i);
    f32x4 d = *(const f32x4*)(p + 3 * S + i);
    s16x4 o = {(short)f2h(a.x + b.x + c.x + d.x), (short)f2h(a.y + b.y + c.y + d.y),
               (short)f2h(a.z + b.z + c.z + d.z), (short)f2h(a.w + b.w + c.w + d.w)};
    *(s16x4*)(MT + i) = o;
}

// wave-per-row in-place softmax on fp16 logits (16384 rows x 1024), no LDS
__global__ __launch_bounds__(256)
void softmax_wave(unsigned short* __restrict__ S)
{
    const int wave = threadIdx.x >> 6, lane = threadIdx.x & 63;
    for (long row = (long)blockIdx.x * 4 + wave; row < 16384; row += (long)gridDim.x * 4) {
        unsigned short* p = S + row * 1024;
        s16x8 ra = *(s16x8*)(p + lane * 8);
        s16x8 rb = *(s16x8*)(p + 512 + lane * 8);
        float va[8], vb[8];
        float m = -3.0e38f;
#pragma unroll
        for (int e = 0; e < 8; ++e) {
            va[e] = h2f((unsigned short)ra[e]); m = fmaxf(m, va[e]);
            vb[e] = h2f((unsigned short)rb[e]); m = fmaxf(m, vb[e]);
        }
#pragma unroll
        for (int off = 1; off < 64; off <<= 1) m = fmaxf(m, __shfl_xor(m, off));
        float s = 0.f;
#pragma unroll
        for (int e = 0; e < 8; ++e) {
            va[e] = expf(va[e] - m); s += va[e];
            vb[e] = expf(vb[e] - m); s += vb[e];
        }
#pragma unroll
        for (int off = 1; off < 64; off <<= 1) s += __shfl_xor(s, off);
        const float inv = 1.f / s;
        s16x8 oa, ob;
#pragma unroll
        for (int e = 0; e < 8; ++e) {
            oa[e] = (short)f2h(va[e] * inv);
            ob[e] = (short)f2h(vb[e] * inv);
        }
        *(s16x8*)(p + lane * 8)       = oa;
        *(s16x8*)(p + 512 + lane * 8) = ob;
    }
}

extern "C" void kernel_launch(void* const* d_in, const int* in_sizes, int n_in,
                              void* d_out, int out_size, void* d_ws, size_t ws_size,
                              hipStream_t stream)
{
    const float* query  = (const float*)d_in[0];
    const float* keys   = (const float*)d_in[1];
    const float* values = (const float*)d_in[2];
    const float* Wq     = (const float*)d_in[3];
    const float* bq     = (const float*)d_in[4];
    const float* Wk     = (const float*)d_in[5];
    const float* bk     = (const float*)d_in[6];   // drops out of softmax
    const float* Wo     = (const float*)d_in[7];
    const float* bo     = (const float*)d_in[8];
    (void)bk;

    const int  T = 1024, H = 1024;
    const long NE = 16384L * 1024;
    const long NW = 1024L * 1024;

    size_t need = (size_t)(NE * 4 + NW * 12 + 40960) * sizeof(unsigned short);
    if (ws_size < need) return;

    unsigned short* ws   = (unsigned short*)d_ws;
    unsigned short* Xq   = ws;                 // -> sc after P1
    unsigned short* Xk   = Xq + NE;
    unsigned short* vT   = Xk + NE;
    unsigned short* P1   = vT + NE;            // -> ctx after scores
    unsigned short* WqT  = P1 + NE;
    unsigned short* WkT  = WqT + NW;
    unsigned short* Woh  = WkT + NW;
    unsigned short* MT   = Woh + NW;
    float*          part = (float*)(MT + NW);
    float*          w2   = (float*)(MT + NW * 9);
    float*          vvec = w2 + 1024;
    unsigned short* sc   = Xq;
    unsigned short* ctx  = P1;

    // ---- prep (w2 first: conv2's keys half consumes it) ----
    w2_kernel<<<16, 256, 0, stream>>>(Wk, bq, w2);
    conv2_f16<<<dim3(8192, 2, 1), 256, 0, stream>>>(query, keys, Xq, Xk, w2, vvec);
    transpose2_f16<<<dim3(32, 32, 2), dim3(32, 8), 0, stream>>>(Wq, Wk, WqT, WkT);
    conv_f16<<<1024, 256, 0, stream>>>(Wo, Woh, (int)NW);
    transpose_vals<<<dim3(32, 32, 4), dim3(32, 8), 0, stream>>>(values, vT);

    // ---- MT = Wk^T * Wq  (split-K=4, grid 4x8x4 = 128 blocks) ----
    gemm128<0><<<dim3(4, 8, 4), 512, 0, stream>>>(
        WkT, WqT, nullptr, part, 1024, 256, 1024, 256, 256, (long)NW, 0, 1.f);
    reduce4<<<1024, 256, 0, stream>>>(part, MT);

    // ---- P1 = Xq . MT^T ----
    gemm128<1><<<dim3(4, 128, 1), 512, 0, stream>>>(
        Xq, MT, nullptr, P1, H, H, H, 0, 0, 0, 0, 1.f);

    // ---- scores = P1 . Xk^T + v[s]  (batched) ----
    gemm128<1><<<dim3(4, 8, 16), 512, 0, stream>>>(
        P1, Xk, vvec, sc, T, H, H,
        (long)T * H, (long)T * H, (long)T * T, (long)T, 1.f);

    // ---- softmax in place (wave per row) ----
    softmax_wave<<<2048, 256, 0, stream>>>(sc);

    // ---- ctx = attn . vT^T / 32  (batched) ----
    gemm128<1><<<dim3(4, 8, 16), 512, 0, stream>>>(
        sc, vT, nullptr, ctx, H, T, T,
        (long)T * T, (long)T * H, (long)T * H, 0, 1.f / 32.f);

    // ---- out = ctx . Wo^T + bo ----
    gemm128<0><<<dim3(4, 128, 1), 512, 0, stream>>>(
        ctx, Woh, bo, d_out, H, H, H, 0, 0, 0, 0, 1.f);
}